// Round 4
// baseline (111.833 us; speedup 1.0000x reference)
//
#include <hip/hip_runtime.h>
#include <stdint.h>
#include <stddef.h>

// SIR scan: B=16384 batches, T=2048 steps, F=2 (beta,gamma), fp32.
// Round 4: 1 consumer wave + 4 PRODUCER waves per block (320 threads).
// Round-3 postmortem: single producer wave capped at ~7.6 B/cyc/CU
// (outstanding-miss limit). Staging is embarrassingly parallel ->
// split each 32 KB chunk across 4 producer waves (one per SIMD),
// each with its own vmcnt counter, counted waits vmcnt(8).
// Consumer wave has ZERO outstanding VMEM in the loop, so compiler-
// inserted drains before its ds_reads are free (round-3 lesson).

#define T_STEPS 2048
#define C_STEPS 64                   // timesteps per chunk
#define NCHUNK  (T_STEPS / C_STEPS)  // 32
#define BPB     64                   // batches per block
#define PAIRS   (C_STEPS / 2)        // 32 float4 slots per batch per chunk
#define IPC     32                   // global_load_lds instrs per 32 KB chunk
#define NPROD   4                    // producer waves
#define SLICE   (IPC / NPROD)        // 8 instrs per producer per chunk

#define INV_POP 1e-6f

// Producer wave w stages its 8 KB slice of chunk c (instrs j = 8w..8w+7).
// LDS dest linear; swizzle carried by the per-lane GLOBAL address (rule #21):
// 16B slot (i, q) <- global step-pair (q ^ (i&15)) of batch i.
// Instruction j covers batches {2j, 2j+1}: lane l -> batch 2j + (l>>5),
// slot q = l&31.
__device__ __forceinline__ void stage_slice(const float* __restrict__ in,
                                            float4* lds, int b0, int c,
                                            int lane, int w)
{
    const int hi = lane >> 5;   // 0 or 1
    const int q  = lane & 31;
#pragma unroll
    for (int jj = 0; jj < SLICE; ++jj) {
        const int j  = w * SLICE + jj;
        const int bi = 2 * j + hi;              // batch within block
        const int p  = q ^ (bi & 15);           // swizzled global pair index
        const float* g = in
            + (size_t)(b0 + bi) * (T_STEPS * 2)
            + (size_t)c * (C_STEPS * 2)
            + (size_t)(p * 4);
        float4* l = lds + j * 64;               // 1 KB per instruction, uniform
        __builtin_amdgcn_global_load_lds(
            (__attribute__((address_space(1))) void*)g,
            (__attribute__((address_space(3))) void*)l,
            16, 0, 0);
    }
}

// Consume one chunk: 32 ds_read_b128 per lane (XOR swizzle -> 8 lanes/bank,
// the wave64-b128 inherent minimum), 64 recurrence steps in time order.
__device__ __forceinline__ void compute_chunk(const float4* lds, int tid,
                                              float& S, float& I, float& R)
{
    const int swz = tid & 15;
    const float4* row = lds + tid * PAIRS;
#pragma unroll
    for (int p = 0; p < PAIRS; ++p) {
        const float4 v = row[p ^ swz];   // steps 2p (v.x,v.y) and 2p+1 (v.z,v.w)

        float ni = S * I * (v.x * INV_POP);
        float nr = v.y * I;
        S = S - ni;
        I = I + ni - nr;
        R = R + nr;

        ni = S * I * (v.z * INV_POP);
        nr = v.w * I;
        S = S - ni;
        I = I + ni - nr;
        R = R + nr;
    }
}

#define BAR()   asm volatile("s_barrier" ::: "memory")
#define WAIT8() asm volatile("s_waitcnt vmcnt(8)" ::: "memory")
#define WAIT0() asm volatile("s_waitcnt vmcnt(0)" ::: "memory")

__global__ __launch_bounds__(64 * (NPROD + 1))
void sir_scan_kernel(const float* __restrict__ in, const float* __restrict__ init,
                     float* __restrict__ out, int half)
{
    // 4 x 32 KB = 128 KB (1 block/CU), statically distinct objects
    __shared__ float4 buf0[BPB * PAIRS];
    __shared__ float4 buf1[BPB * PAIRS];
    __shared__ float4 buf2[BPB * PAIRS];
    __shared__ float4 buf3[BPB * PAIRS];

    const int tid = threadIdx.x;
    const int b0  = blockIdx.x * BPB;

    if (tid < 64) {
        // ---------------- consumer wave: zero outstanding VMEM in the loop
        const int gb = b0 + tid;
        float S = init[gb * 3 + 0];
        float I = init[gb * 3 + 1];
        float R = init[gb * 3 + 2];

        // BAR #c <=> "chunk c has landed" (every producer waits before it)
#pragma unroll 1
        for (int c = 0; c < NCHUNK; c += 4) {
            BAR(); compute_chunk(buf0, tid, S, I, R);
            BAR(); compute_chunk(buf1, tid, S, I, R);
            BAR(); compute_chunk(buf2, tid, S, I, R);
            BAR(); compute_chunk(buf3, tid, S, I, R);
        }

        out[gb * 3 + 0] = S;
        out[gb * 3 + 1] = I;
        out[gb * 3 + 2] = R;
        out[half + gb * 3 + 0] = S;
        out[half + gb * 3 + 1] = I;
        out[half + gb * 3 + 2] = R;
    } else {
        // ---------------- producer waves: staging + counted waits only
        const int lane = tid & 63;
        const int w    = (tid >> 6) - 1;   // 0..3

        stage_slice(in, buf0, b0, 0, lane, w);
        stage_slice(in, buf1, b0, 1, lane, w);

        // Invariant at each WAIT8: this wave's outstanding = slices of
        // {c, c+1} (16 instrs); vmcnt(8) => chunk c's slice landed.
        // After BAR #c we stage chunk c+2 into buf[(c+2)%4] =
        // buf[(c-2)%4], read-finished by the consumer 2 barriers ago.
#pragma unroll 1
        for (int c = 0; c < NCHUNK - 4; c += 4) {
            WAIT8(); BAR(); stage_slice(in, buf2, b0, c + 2, lane, w);
            WAIT8(); BAR(); stage_slice(in, buf3, b0, c + 3, lane, w);
            WAIT8(); BAR(); stage_slice(in, buf0, b0, c + 4, lane, w);
            WAIT8(); BAR(); stage_slice(in, buf1, b0, c + 5, lane, w);
        }
        // chunks 28..31: stage only 30, 31
        WAIT8(); BAR(); stage_slice(in, buf2, b0, NCHUNK - 2, lane, w);
        WAIT8(); BAR(); stage_slice(in, buf3, b0, NCHUNK - 1, lane, w);
        WAIT8(); BAR();   // chunk 30 landed (outstanding {30,31} slices)
        WAIT0(); BAR();   // chunk 31 landed
    }
}

extern "C" void kernel_launch(void* const* d_in, const int* in_sizes, int n_in,
                              void* d_out, int out_size, void* d_ws, size_t ws_size,
                              hipStream_t stream) {
    (void)in_sizes; (void)n_in; (void)d_ws; (void)ws_size;
    const float* in   = (const float*)d_in[0];   // (B, T, 2) fp32
    const float* init = (const float*)d_in[1];   // (B, 3)    fp32
    float* out        = (float*)d_out;           // 2 x (B, 3) fp32, concatenated
    const int half = out_size / 2;

    dim3 grid(16384 / BPB);          // 256 blocks, 1 per CU
    dim3 block(64 * (NPROD + 1));    // wave 0 consumer, waves 1..4 producers
    sir_scan_kernel<<<grid, block, 0, stream>>>(in, init, out, half);
}